// Round 15
// baseline (218.370 us; speedup 1.0000x reference)
//
#include <hip/hip_runtime.h>

#define NJ 24
#define NV 6890
#define NB 1024
#define NRQ 218       // 1 + 10 betas + 207 pose
#define QPAD 224
#define NCOLR 654     // real data columns (218*3)
#define DPAD 704      // DT rows (11 x 64 n-tiles)
#define VPAD 7040     // DT cols (v padded to 10 x 704)
#define EDIM 1728     // 576*3
#define NZ 10         // split-K chunks
#define KCH 704       // vertices per chunk (22 x 32)
#define MROWS 576     // P m-rows (9 x 64 tiles, KQ only)
#define PPAD 656      // P row stride
#define PSLAB (MROWS * PPAD)   // 377,856 floats per z-slab

typedef __attribute__((ext_vector_type(8))) short short8;
typedef __attribute__((ext_vector_type(4))) float floatx4;

// ---- workspace layout (bytes), total 40,650,112 (validated guard) ----
constexpr size_t OFF_P  = 0;                       // P  f32 [10][576][656] 15,114,240
constexpr size_t OFF_M  = 0;                       // M  f32 [NB][EDIM]      7,077,888 (aliases P)
constexpr size_t OFF_D  = 17638400;                // DT bf16 [704][7040]    9,912,320
constexpr size_t OFF_KQ = 37040640;                // KQ f32 [NRQ][EDIM]     1,506,816
constexpr size_t OFF_W  = 38547456;                // W  f32 [576]               2,304
constexpr size_t OFF_JQ = 38549760;                // JQ f32 [11][72]            3,200
constexpr size_t OFF_Q  = 38552960;                // qT f32 [QPAD][NB]        917,504
constexpr size_t OFF_A  = 39470464;                // A  f32 [NB][288]       1,179,648
constexpr size_t TOTAL_WS = 40650112;

__device__ __forceinline__ unsigned short f2bf(float f) {
  union { float f; unsigned int i; } v; v.f = f;
  unsigned int r = v.i + 0x7FFFu + ((v.i >> 16) & 1u);
  return (unsigned short)(r >> 16);
}

// =================== fast path kernels ===================

// DT[n][v] bf16 = src_r[3v+c] (n=3r+c<654), 1.0 (n==654, v<NV), 0 pad.
// Grid (110 v-tiles of 64, 10 r-tiles of 24). Coalesced reads & writes.
__global__ __launch_bounds__(256) void k_dfill(const float* __restrict__ vt,
                                               const float* __restrict__ sd,
                                               const float* __restrict__ pd,
                                               unsigned short* __restrict__ DT) {
  __shared__ float Dt2[72][68];
  const int t  = threadIdx.x;
  const int v0 = blockIdx.x * 64;
  const int rt = blockIdx.y;
  const int r0 = rt * 24;
  for (int i = t; i < 72 * 68; i += 256) ((float*)Dt2)[i] = 0.f;
  __syncthreads();
  for (int lin = t; lin < 24 * 48; lin += 256) {
    const int r  = lin / 48;
    const int i4 = lin - r * 48;
    const int rr = r0 + r;
    float4 val = make_float4(0.f, 0.f, 0.f, 0.f);
    float* pv = (float*)&val;
    if (rr < 218) {
      const float* __restrict__ S = (rr == 0) ? vt
                                  : (rr <= 10) ? (sd + (size_t)(rr - 1) * 20670)
                                               : (pd + (size_t)(rr - 11) * 20670);
      const int base = 3 * v0 + 4 * i4;
      if (base + 3 < NV * 3) {
        val = *(const float4*)(S + base);
      } else {
        #pragma unroll
        for (int u = 0; u < 4; ++u) if (base + u < NV * 3) pv[u] = S[base + u];
      }
    } else if (rr == 218) {
      #pragma unroll
      for (int u = 0; u < 4; ++u) {
        const int i = 4 * i4 + u;
        if ((i % 3) == 0 && v0 + i / 3 < NV) pv[u] = 1.0f;
      }
    }
    #pragma unroll
    for (int u = 0; u < 4; ++u) {
      const int i = 4 * i4 + u;
      Dt2[3 * r + (i % 3)][i / 3] = pv[u];
    }
  }
  __syncthreads();
  for (int lin = t; lin < 72 * 8; lin += 256) {
    const int nl = lin / 8, ch = lin - nl * 8;
    const int n = rt * 72 + nl;
    if (n < DPAD) {
      unsigned short u8[8];
      #pragma unroll
      for (int u = 0; u < 8; ++u) u8[u] = f2bf(Dt2[nl][ch * 8 + u]);
      *(uint4*)&DT[(size_t)n * VPAD + v0 + ch * 8] = *(uint4*)u8;
    }
  }
}

// fp32-exact W[576] and JQ[11][72] (precision-critical translation path).
// One wave per output group; 840 waves = 210 blocks.
__global__ __launch_bounds__(256) void k_wjq(const float* __restrict__ Jr,
                                             const float* __restrict__ wts,
                                             const float* __restrict__ vt,
                                             const float* __restrict__ sd,
                                             float* __restrict__ W,
                                             float* __restrict__ JQ) {
  const int wid = blockIdx.x * 4 + (threadIdx.x >> 6);
  const int lane = threadIdx.x & 63;
  if (wid < 576) {
    const int jj = wid / 24, j = wid - jj * 24;
    float s = 0.f;
    for (int v = lane; v < NV; v += 64) s += Jr[v * NJ + jj] * wts[v * NJ + j];
    #pragma unroll
    for (int off = 32; off > 0; off >>= 1) s += __shfl_down(s, off, 64);
    if (lane == 0) W[wid] = s;
  } else if (wid < 840) {
    const int idx = wid - 576;
    const int r = idx / 24, j = idx - r * 24;
    const float* __restrict__ S = (r == 0) ? vt : (sd + (size_t)(r - 1) * 20670);
    float a0 = 0.f, a1 = 0.f, a2 = 0.f;
    for (int v = lane; v < NV; v += 64) {
      const float g = Jr[v * NJ + j];
      a0 += g * S[3 * v + 0];
      a1 += g * S[3 * v + 1];
      a2 += g * S[3 * v + 2];
    }
    #pragma unroll
    for (int off = 32; off > 0; off >>= 1) {
      a0 += __shfl_down(a0, off, 64);
      a1 += __shfl_down(a1, off, 64);
      a2 += __shfl_down(a2, off, 64);
    }
    if (lane == 0) {
      JQ[r * 72 + j * 3 + 0] = a0;
      JQ[r * 72 + j * 3 + 1] = a1;
      JQ[r * 72 + j * 3 + 2] = a2;
    }
  }
}

// P[z][m][n] = sum_v G[v][m]*D[v][n] via bf16 MFMA 16x16x32, fp32 acc.
// 64x64 tile, 4 waves (wave -> 16 m-rows x 64 n). A generated in registers
// from Jr/wts; B staged from bf16 DT. Grid (11 n, 9 m, 10 z) = 990 blocks.
__global__ __launch_bounds__(256) void k_gemm1(const float* __restrict__ Jr,
                                               const float* __restrict__ wts,
                                               const unsigned short* __restrict__ DT,
                                               float* __restrict__ P) {
  __shared__ unsigned short Bt[64][40];   // [n][k] bf16, padded stride 40
  const int t = threadIdx.x;
  const int n0 = blockIdx.x * 64;
  const int m0 = blockIdx.y * 64;
  const int z  = blockIdx.z;
  const int kbeg = z * KCH;
  const int wv = t >> 6, lane = t & 63;
  const int quad = lane >> 4, l16 = lane & 15;
  const int m = m0 + wv * 16 + l16;       // < 576 always
  const int jjm = m / 24, jm = m - 24 * jjm;
  const int sn = t & 63, skg = t >> 6;    // staging: n row, k-group

  floatx4 acc[4] = {{0.f,0.f,0.f,0.f},{0.f,0.f,0.f,0.f},{0.f,0.f,0.f,0.f},{0.f,0.f,0.f,0.f}};
  for (int s = 0; s < 22; ++s) {
    const int k0 = kbeg + s * 32;
    // stage B tile (32k x 64n) as Bt[n][k]
    *(uint4*)&Bt[sn][skg * 8] = *(const uint4*)&DT[(size_t)(n0 + sn) * VPAD + k0 + skg * 8];
    // A fragment in registers: A[m=l16][k=quad*8+j] = Jr[v][jjm]*wts[v][jm]
    short8 af;
    #pragma unroll
    for (int j = 0; j < 8; ++j) {
      const int v = k0 + quad * 8 + j;
      float g = 0.f;
      if (v < NV) g = Jr[v * NJ + jjm] * wts[v * NJ + jm];
      af[j] = (short)f2bf(g);
    }
    __syncthreads();
    #pragma unroll
    for (int nf = 0; nf < 4; ++nf) {
      short8 bf = *(const short8*)&Bt[l16 + nf * 16][quad * 8];
      acc[nf] = __builtin_amdgcn_mfma_f32_16x16x32_bf16(af, bf, acc[nf], 0, 0, 0);
    }
    __syncthreads();
  }
  // C/D layout (m89-verified): row m = quad*4 + reg, col n = lane&15
  float* __restrict__ Pz = P + (size_t)z * PSLAB;
  #pragma unroll
  for (int nf = 0; nf < 4; ++nf) {
    const int n_out = n0 + nf * 16 + l16;
    if (n_out < PPAD) {
      #pragma unroll
      for (int r = 0; r < 4; ++r) {
        const int m_out = m0 + wv * 16 + quad * 4 + r;
        Pz[(size_t)m_out * PPAD + n_out] = acc[nf][r];
      }
    }
  }
}

// sum the split-K partials into KQ (W/JQ come from k_wjq)
__global__ __launch_bounds__(256) void k_reduce(const float* __restrict__ P,
                                                float* __restrict__ KQ) {
  const int m = blockIdx.x;           // 0..575
  for (int n = threadIdx.x; n < NCOLR; n += 256) {
    float s = 0.f;
    #pragma unroll
    for (int zz = 0; zz < NZ; ++zz)
      s += P[(size_t)zz * PSLAB + (size_t)m * PPAD + n];
    const int rr = n / 3, c = n - 3 * rr;
    KQ[(size_t)rr * EDIM + m * 3 + c] = s;
  }
}

// per-batch Rodrigues + chain -> A[b][288], qT[r][b]
__global__ __launch_bounds__(64) void k_chain(const float* __restrict__ beta,
                                              const float* __restrict__ theta,
                                              const float* __restrict__ JQ,
                                              float* __restrict__ qT,
                                              float* __restrict__ A) {
  const int b = blockIdx.x;
  const int t = threadIdx.x;
  __shared__ float RES[24][12];
  __shared__ float Jl[24][3];
  const int par[24] = {-1,0,0,0,1,2,3,4,5,6,7,8,9,9,9,12,13,14,16,17,18,19,20,21};
  const int dep[24] = {0,1,1,1,2,2,2,3,3,3,4,4,4,4,4,5,5,5,6,6,7,7,8,8};
  float R[9];
  float Jv[3];
  if (t < 6) qT[(size_t)(NRQ + t) * NB + b] = 0.f;
  if (t < NJ) {
    const int j = t;
    const float th0 = theta[b * 72 + j * 3 + 0];
    const float th1 = theta[b * 72 + j * 3 + 1];
    const float th2 = theta[b * 72 + j * 3 + 2];
    const float a0 = th0 + 1e-8f, a1 = th1 + 1e-8f, a2 = th2 + 1e-8f;
    const float angle = sqrtf(a0 * a0 + a1 * a1 + a2 * a2);
    const float inv = 1.0f / angle;
    const float half = 0.5f * angle;
    const float cw = cosf(half), sv = sinf(half);
    float qw = cw, qx = sv * th0 * inv, qy = sv * th1 * inv, qz = sv * th2 * inv;
    const float qn = 1.0f / sqrtf(qw * qw + qx * qx + qy * qy + qz * qz);
    qw *= qn; qx *= qn; qy *= qn; qz *= qn;
    const float w2 = qw * qw, x2 = qx * qx, y2 = qy * qy, z2 = qz * qz;
    const float wx = qw * qx, wy = qw * qy, wz = qw * qz;
    const float xy = qx * qy, xz = qx * qz, yz = qy * qz;
    R[0] = w2 + x2 - y2 - z2; R[1] = 2.f * (xy - wz);   R[2] = 2.f * (xz + wy);
    R[3] = 2.f * (xy + wz);   R[4] = w2 - x2 + y2 - z2; R[5] = 2.f * (yz - wx);
    R[6] = 2.f * (xz - wy);   R[7] = 2.f * (yz + wx);   R[8] = w2 - x2 - y2 + z2;
    float betaf[10];
    #pragma unroll
    for (int s = 0; s < 10; ++s) betaf[s] = beta[b * 10 + s];
    #pragma unroll
    for (int c = 0; c < 3; ++c) {
      float jv = JQ[j * 3 + c];
      #pragma unroll
      for (int s = 0; s < 10; ++s) jv += betaf[s] * JQ[(1 + s) * 72 + j * 3 + c];
      Jv[c] = jv; Jl[j][c] = jv;
    }
    if (j >= 1) {
      #pragma unroll
      for (int k = 0; k < 9; ++k)
        qT[(size_t)(11 + (j - 1) * 9 + k) * NB + b] = R[k] - ((k == 0 || k == 4 || k == 8) ? 1.f : 0.f);
    }
    if (j == 0) qT[b] = 1.f;
    if (j < 10) qT[(size_t)(1 + j) * NB + b] = betaf[j];
  }
  __syncthreads();
  for (int lvl = 0; lvl < 9; ++lvl) {
    if (t < NJ && dep[t] == lvl) {
      if (t == 0) {
        #pragma unroll
        for (int i = 0; i < 3; ++i) {
          RES[0][i * 4 + 0] = R[i * 3 + 0]; RES[0][i * 4 + 1] = R[i * 3 + 1];
          RES[0][i * 4 + 2] = R[i * 3 + 2]; RES[0][i * 4 + 3] = Jv[i];
        }
      } else {
        const int p = par[t];
        const float tr0 = Jv[0] - Jl[p][0];
        const float tr1 = Jv[1] - Jl[p][1];
        const float tr2 = Jv[2] - Jl[p][2];
        float Pr[12];
        #pragma unroll
        for (int k = 0; k < 12; ++k) Pr[k] = RES[p][k];
        #pragma unroll
        for (int i = 0; i < 3; ++i) {
          const float r0 = Pr[i*4+0], r1 = Pr[i*4+1], r2 = Pr[i*4+2], r3 = Pr[i*4+3];
          RES[t][i * 4 + 0] = r0 * R[0] + r1 * R[3] + r2 * R[6];
          RES[t][i * 4 + 1] = r0 * R[1] + r1 * R[4] + r2 * R[7];
          RES[t][i * 4 + 2] = r0 * R[2] + r1 * R[5] + r2 * R[8];
          RES[t][i * 4 + 3] = r0 * tr0 + r1 * tr1 + r2 * tr2 + r3;
        }
      }
    }
    __syncthreads();
  }
  if (t < NJ) {
    float* Ab = A + (size_t)b * 288 + t * 12;
    #pragma unroll
    for (int i = 0; i < 3; ++i) {
      const float r0 = RES[t][i*4+0], r1 = RES[t][i*4+1], r2 = RES[t][i*4+2];
      const float ti = RES[t][i*4+3] - (r0 * Jv[0] + r1 * Jv[1] + r2 * Jv[2]);
      Ab[i*4+0] = r0; Ab[i*4+1] = r1; Ab[i*4+2] = r2; Ab[i*4+3] = ti;
    }
  }
}

// M[b][e] = sum_r qT[r][b] * KQ[r][e]; 64(b) x 64(e) tile, 4x4 acc, K=224
__global__ __launch_bounds__(256) void k_mgemm(const float* __restrict__ qT,
                                               const float* __restrict__ KQ,
                                               float* __restrict__ M) {
  __shared__ float Qs[16][64];
  __shared__ float Ks[16][64];
  const int t = threadIdx.x;
  const int e0 = blockIdx.x * 64;
  const int b0 = blockIdx.y * 64;
  const int tb = (t & 15) * 4;
  const int te = (t >> 4) * 4;
  const int skk = t >> 4;
  const int sc  = (t & 15) * 4;
  float acc[4][4] = {};
  for (int k0 = 0; k0 < QPAD; k0 += 16) {
    const int k = k0 + skk;
    *(float4*)&Qs[skk][sc] = *(const float4*)&qT[(size_t)k * NB + b0 + sc];
    if (k < NRQ) *(float4*)&Ks[skk][sc] = *(const float4*)&KQ[(size_t)k * EDIM + e0 + sc];
    else         *(float4*)&Ks[skk][sc] = make_float4(0.f, 0.f, 0.f, 0.f);
    __syncthreads();
    #pragma unroll
    for (int kk = 0; kk < 16; ++kk) {
      float4 qv = *(const float4*)&Qs[kk][tb];
      float4 kv = *(const float4*)&Ks[kk][te];
      const float qa[4] = {qv.x, qv.y, qv.z, qv.w};
      const float ka[4] = {kv.x, kv.y, kv.z, kv.w};
      #pragma unroll
      for (int i = 0; i < 4; ++i)
        #pragma unroll
        for (int j = 0; j < 4; ++j)
          acc[i][j] += qa[i] * ka[j];
    }
    __syncthreads();
  }
  #pragma unroll
  for (int i = 0; i < 4; ++i) {
    float4 st = make_float4(acc[i][0], acc[i][1], acc[i][2], acc[i][3]);
    *(float4*)&M[(size_t)(b0 + tb + i) * EDIM + e0 + te] = st;
  }
}

// joints[b,jj,i] = sum_j( A[b,j,i,:3] . M[b,(jj,j)*3..] + A[b,j,i,3]*W[jj,j] )
__global__ __launch_bounds__(256) void k_joints(const float* __restrict__ M,
                                                const float* __restrict__ A,
                                                const float* __restrict__ W,
                                                float* __restrict__ out) {
  const int b = blockIdx.x;
  const int t = threadIdx.x;
  __shared__ float Ml[EDIM];
  __shared__ float Al[288];
  __shared__ float Wl[576];
  {
    const float4* Mg = (const float4*)(M + (size_t)b * EDIM);
    float4* Ms = (float4*)Ml;
    for (int i = t; i < EDIM / 4; i += 256) Ms[i] = Mg[i];
    if (t < 72)  ((float4*)Al)[t] = ((const float4*)(A + (size_t)b * 288))[t];
    if (t < 144) ((float4*)Wl)[t] = ((const float4*)W)[t];
  }
  __syncthreads();
  if (t < 72) {
    const int jj = t / 3, i = t - jj * 3;
    float acc = 0.f;
    #pragma unroll
    for (int j = 0; j < NJ; ++j) {
      const float* Ar = &Al[j * 12 + i * 4];
      const int base = (jj * NJ + j) * 3;
      acc += Ar[0] * Ml[base] + Ar[1] * Ml[base + 1]
           + Ar[2] * Ml[base + 2] + Ar[3] * Wl[jj * NJ + j];
    }
    out[(size_t)b * 72 + t] = acc;
  }
}

// =================== fallback: validated monolithic kernel (R5) ===================
__global__ __launch_bounds__(256) void k_all(
    const float* __restrict__ beta,
    const float* __restrict__ theta,
    const float* __restrict__ vt,
    const float* __restrict__ sd,
    const float* __restrict__ pd,
    const float* __restrict__ Jr,
    const float* __restrict__ wts,
    float* __restrict__ out) {
  const int b = blockIdx.x;
  const int t = threadIdx.x;
  __shared__ float vs[NV * 3];
  __shared__ float bl[10];
  __shared__ float pf[207];
  __shared__ float Am[NJ * 12];
  __shared__ float Jl[NJ * 3];
  __shared__ float jpart[72 * 3];
  __shared__ float jred[72];
  if (t < 10) bl[t] = beta[b * 10 + t];
  if (t < 72) jred[t] = 0.f;
  __syncthreads();
  for (int e = t; e < NV * 3; e += 256) {
    float val = vt[e];
    #pragma unroll
    for (int s = 0; s < 10; ++s) val += bl[s] * sd[s * 20670 + e];
    vs[e] = val;
  }
  __syncthreads();
  if (t < 216) {
    const int o = t % 72, part = t / 72;
    const int j = o / 3, c = o - j * 3;
    float local = 0.f;
    for (int v = part; v < NV; v += 3)
      local += Jr[v * NJ + j] * vs[v * 3 + c];
    jpart[o * 3 + part] = local;
  }
  __syncthreads();
  if (t < 72) Jl[t] = jpart[t * 3] + jpart[t * 3 + 1] + jpart[t * 3 + 2];
  __syncthreads();
  const int par[24] = {-1,0,0,0,1,2,3,4,5,6,7,8,9,9,9,12,13,14,16,17,18,19,20,21};
  const int dep[24] = {0,1,1,1,2,2,2,3,3,3,4,4,4,4,4,5,5,5,6,6,7,7,8,8};
  float R[9];
  float Jv[3];
  if (t < NJ) {
    const int j = t;
    const float th0 = theta[b * 72 + j * 3 + 0];
    const float th1 = theta[b * 72 + j * 3 + 1];
    const float th2 = theta[b * 72 + j * 3 + 2];
    const float a0 = th0 + 1e-8f, a1 = th1 + 1e-8f, a2 = th2 + 1e-8f;
    const float angle = sqrtf(a0 * a0 + a1 * a1 + a2 * a2);
    const float inv = 1.0f / angle;
    const float half = 0.5f * angle;
    const float cw = cosf(half), sv = sinf(half);
    float qw = cw, qx = sv * th0 * inv, qy = sv * th1 * inv, qz = sv * th2 * inv;
    const float qn = 1.0f / sqrtf(qw * qw + qx * qx + qy * qy + qz * qz);
    qw *= qn; qx *= qn; qy *= qn; qz *= qn;
    const float w2 = qw * qw, x2 = qx * qx, y2 = qy * qy, z2 = qz * qz;
    const float wx = qw * qx, wy = qw * qy, wz = qw * qz;
    const float xy = qx * qy, xz = qx * qz, yz = qy * qz;
    R[0] = w2 + x2 - y2 - z2; R[1] = 2.f * (xy - wz);   R[2] = 2.f * (xz + wy);
    R[3] = 2.f * (xy + wz);   R[4] = w2 - x2 + y2 - z2; R[5] = 2.f * (yz - wx);
    R[6] = 2.f * (xz - wy);   R[7] = 2.f * (yz + wx);   R[8] = w2 - x2 - y2 + z2;
    #pragma unroll
    for (int c = 0; c < 3; ++c) Jv[c] = Jl[j * 3 + c];
    if (j >= 1) {
      #pragma unroll
      for (int k = 0; k < 9; ++k)
        pf[(j - 1) * 9 + k] = R[k] - ((k == 0 || k == 4 || k == 8) ? 1.f : 0.f);
    }
  }
  __syncthreads();
  for (int lvl = 0; lvl < 9; ++lvl) {
    if (t < NJ && dep[t] == lvl) {
      if (t == 0) {
        #pragma unroll
        for (int i = 0; i < 3; ++i) {
          Am[i * 4 + 0] = R[i * 3 + 0]; Am[i * 4 + 1] = R[i * 3 + 1];
          Am[i * 4 + 2] = R[i * 3 + 2]; Am[i * 4 + 3] = Jv[i];
        }
      } else {
        const int p = par[t];
        const float tr0 = Jv[0] - Jl[p * 3 + 0];
        const float tr1 = Jv[1] - Jl[p * 3 + 1];
        const float tr2 = Jv[2] - Jl[p * 3 + 2];
        float Pr[12];
        #pragma unroll
        for (int k = 0; k < 12; ++k) Pr[k] = Am[p * 12 + k];
        #pragma unroll
        for (int i = 0; i < 3; ++i) {
          const float r0 = Pr[i*4+0], r1 = Pr[i*4+1], r2 = Pr[i*4+2], r3 = Pr[i*4+3];
          Am[t * 12 + i * 4 + 0] = r0 * R[0] + r1 * R[3] + r2 * R[6];
          Am[t * 12 + i * 4 + 1] = r0 * R[1] + r1 * R[4] + r2 * R[7];
          Am[t * 12 + i * 4 + 2] = r0 * R[2] + r1 * R[5] + r2 * R[8];
          Am[t * 12 + i * 4 + 3] = r0 * tr0 + r1 * tr1 + r2 * tr2 + r3;
        }
      }
    }
    __syncthreads();
  }
  if (t < NJ) {
    float res[12];
    #pragma unroll
    for (int k = 0; k < 12; ++k) res[k] = Am[t * 12 + k];
    #pragma unroll
    for (int i = 0; i < 3; ++i) {
      const float r0 = res[i * 4 + 0], r1 = res[i * 4 + 1], r2 = res[i * 4 + 2];
      Am[t * 12 + i * 4 + 3] = res[i * 4 + 3] - (r0 * Jv[0] + r1 * Jv[1] + r2 * Jv[2]);
    }
  }
  __syncthreads();
  for (int r = 0; r < 207; ++r) {
    const float f = pf[r];
    const float* __restrict__ pr = pd + (size_t)r * 20670;
    for (int e = t; e < NV * 3; e += 256) vs[e] += f * pr[e];
  }
  __syncthreads();
  float jacc[72];
  #pragma unroll
  for (int k = 0; k < 72; ++k) jacc[k] = 0.f;
  for (int v = t; v < NV; v += 256) {
    const float vp0 = vs[3 * v + 0];
    const float vp1 = vs[3 * v + 1];
    const float vp2 = vs[3 * v + 2];
    float tA[12];
    #pragma unroll
    for (int k = 0; k < 12; ++k) tA[k] = 0.f;
    const float* __restrict__ wp = wts + (size_t)v * NJ;
    #pragma unroll
    for (int j = 0; j < NJ; ++j) {
      const float wj = wp[j];
      #pragma unroll
      for (int k = 0; k < 12; ++k) tA[k] += wj * Am[j * 12 + k];
    }
    const float vx = tA[0] * vp0 + tA[1] * vp1 + tA[2]  * vp2 + tA[3];
    const float vy = tA[4] * vp0 + tA[5] * vp1 + tA[6]  * vp2 + tA[7];
    const float vz = tA[8] * vp0 + tA[9] * vp1 + tA[10] * vp2 + tA[11];
    const float* __restrict__ jp = Jr + (size_t)v * NJ;
    #pragma unroll
    for (int jj = 0; jj < NJ; ++jj) {
      const float g = jp[jj];
      jacc[jj * 3 + 0] += g * vx;
      jacc[jj * 3 + 1] += g * vy;
      jacc[jj * 3 + 2] += g * vz;
    }
  }
  #pragma unroll
  for (int k = 0; k < 72; ++k) atomicAdd(&jred[k], jacc[k]);
  __syncthreads();
  if (t < 72) out[(size_t)b * 72 + t] = jred[t];
}

extern "C" void kernel_launch(void* const* d_in, const int* in_sizes, int n_in,
                              void* d_out, int out_size, void* d_ws, size_t ws_size,
                              hipStream_t stream) {
  const float* beta  = (const float*)d_in[0];
  const float* theta = (const float*)d_in[1];
  const float* vt    = (const float*)d_in[2];
  const float* sd    = (const float*)d_in[3];
  const float* pd    = (const float*)d_in[4];
  const float* Jr    = (const float*)d_in[5];
  const float* wts   = (const float*)d_in[6];
  float* out = (float*)d_out;
  (void)in_sizes; (void)n_in; (void)out_size;

  if (ws_size >= TOTAL_WS) {
    char* ws = (char*)d_ws;
    float* P  = (float*)(ws + OFF_P);
    unsigned short* DT = (unsigned short*)(ws + OFF_D);
    float* KQ = (float*)(ws + OFF_KQ);
    float* W  = (float*)(ws + OFF_W);
    float* JQ = (float*)(ws + OFF_JQ);
    float* qT = (float*)(ws + OFF_Q);
    float* A  = (float*)(ws + OFF_A);
    float* M  = (float*)(ws + OFF_M);   // aliases P (P dead after k_reduce)

    k_dfill<<<dim3(VPAD / 64, 10), 256, 0, stream>>>(vt, sd, pd, DT);
    k_wjq<<<210, 256, 0, stream>>>(Jr, wts, vt, sd, W, JQ);
    k_gemm1<<<dim3(11, 9, NZ), 256, 0, stream>>>(Jr, wts, DT, P);
    k_reduce<<<MROWS, 256, 0, stream>>>(P, KQ);
    k_chain<<<NB, 64, 0, stream>>>(beta, theta, JQ, qT, A);
    k_mgemm<<<dim3(27, 16), 256, 0, stream>>>(qT, KQ, M);
    k_joints<<<NB, 256, 0, stream>>>(M, A, W, out);
  } else {
    k_all<<<NB, 256, 0, stream>>>(beta, theta, vt, sd, pd, Jr, wts, out);
  }
}

// Round 16
// 169.950 us; speedup vs baseline: 1.2849x; 1.2849x over previous
//
#include <hip/hip_runtime.h>

#define NJ 24
#define NV 6890
#define NB 1024
#define NRQ 218       // 1 + 10 betas + 207 pose
#define QPAD 224
#define NCOLR 654     // real data columns (218*3)
#define DPAD 704      // DT rows (11 x 64 n-tiles)
#define VPAD 7040     // DT/GT cols (v padded)
#define EDIM 1728     // 576*3
#define NZ 10         // split-K chunks
#define KCH 704       // vertices per chunk (22 x 32)
#define MROWS 576     // P m-rows (9 x 64 tiles, KQ only)
#define PPAD 656      // P row stride
#define PSLAB (MROWS * PPAD)   // 377,856 floats per z-slab

typedef __attribute__((ext_vector_type(8))) short short8;
typedef __attribute__((ext_vector_type(4))) float floatx4;

// ---- workspace layout (bytes), total 40,650,112 (validated guard) ----
constexpr size_t OFF_P  = 0;                       // P  f32 [10][576][656] 15,114,240
constexpr size_t OFF_M  = 0;                       // M  f32 [NB][EDIM]      7,077,888 (aliases P)
constexpr size_t OFF_D  = 17638400;                // DT bf16 [704][7040]    9,912,320 (ends 27,550,720)
constexpr size_t OFF_GT = 27550720;                // GT bf16 [576][7040]    8,110,080 (ends 35,660,800)
constexpr size_t OFF_KQ = 37040640;                // KQ f32 [NRQ][EDIM]     1,506,816
constexpr size_t OFF_W  = 38547456;                // W  f32 [576]               2,304
constexpr size_t OFF_JQ = 38549760;                // JQ f32 [11][72]            3,200
constexpr size_t OFF_Q  = 38552960;                // qT f32 [QPAD][NB]        917,504
constexpr size_t OFF_A  = 39470464;                // A  f32 [NB][288]       1,179,648
constexpr size_t TOTAL_WS = 40650112;

__device__ __forceinline__ unsigned short f2bf(float f) {
  union { float f; unsigned int i; } v; v.f = f;
  unsigned int r = v.i + 0x7FFFu + ((v.i >> 16) & 1u);
  return (unsigned short)(r >> 16);
}

// =================== fast path kernels ===================

// DT[n][v] bf16 = src_r[3v+c] (n=3r+c<654), 1.0 (n==654, v<NV), 0 pad.
__global__ __launch_bounds__(256) void k_dfill(const float* __restrict__ vt,
                                               const float* __restrict__ sd,
                                               const float* __restrict__ pd,
                                               unsigned short* __restrict__ DT) {
  __shared__ float Dt2[72][68];
  const int t  = threadIdx.x;
  const int v0 = blockIdx.x * 64;
  const int rt = blockIdx.y;
  const int r0 = rt * 24;
  for (int i = t; i < 72 * 68; i += 256) ((float*)Dt2)[i] = 0.f;
  __syncthreads();
  for (int lin = t; lin < 24 * 48; lin += 256) {
    const int r  = lin / 48;
    const int i4 = lin - r * 48;
    const int rr = r0 + r;
    float4 val = make_float4(0.f, 0.f, 0.f, 0.f);
    float* pv = (float*)&val;
    if (rr < 218) {
      const float* __restrict__ S = (rr == 0) ? vt
                                  : (rr <= 10) ? (sd + (size_t)(rr - 1) * 20670)
                                               : (pd + (size_t)(rr - 11) * 20670);
      const int base = 3 * v0 + 4 * i4;
      if (base + 3 < NV * 3) {
        val = *(const float4*)(S + base);
      } else {
        #pragma unroll
        for (int u = 0; u < 4; ++u) if (base + u < NV * 3) pv[u] = S[base + u];
      }
    } else if (rr == 218) {
      #pragma unroll
      for (int u = 0; u < 4; ++u) {
        const int i = 4 * i4 + u;
        if ((i % 3) == 0 && v0 + i / 3 < NV) pv[u] = 1.0f;
      }
    }
    #pragma unroll
    for (int u = 0; u < 4; ++u) {
      const int i = 4 * i4 + u;
      Dt2[3 * r + (i % 3)][i / 3] = pv[u];
    }
  }
  __syncthreads();
  for (int lin = t; lin < 72 * 8; lin += 256) {
    const int nl = lin / 8, ch = lin - nl * 8;
    const int n = rt * 72 + nl;
    if (n < DPAD) {
      unsigned short u8[8];
      #pragma unroll
      for (int u = 0; u < 8; ++u) u8[u] = f2bf(Dt2[nl][ch * 8 + u]);
      *(uint4*)&DT[(size_t)n * VPAD + v0 + ch * 8] = *(uint4*)u8;
    }
  }
}

// GT[m][v] bf16 = Jr[v][m/24]*wts[v][m%24]; zeros for v >= NV. Grid 110 blocks.
__global__ __launch_bounds__(256) void k_gfill(const float* __restrict__ Jr,
                                               const float* __restrict__ wts,
                                               unsigned short* __restrict__ GT) {
  __shared__ float JrS[64][24];
  __shared__ float WtS[64][24];
  const int t  = threadIdx.x;
  const int v0 = blockIdx.x * 64;
  for (int lin = t; lin < 64 * 6; lin += 256) {       // 64 rows x 6 float4
    const int row = lin / 6, q = lin - row * 6;
    const int v = v0 + row;
    float4 a = make_float4(0.f, 0.f, 0.f, 0.f), b = a;
    if (v < NV) {
      a = *(const float4*)(Jr  + (size_t)v * NJ + q * 4);
      b = *(const float4*)(wts + (size_t)v * NJ + q * 4);
    }
    *(float4*)&JrS[row][q * 4] = a;
    *(float4*)&WtS[row][q * 4] = b;
  }
  __syncthreads();
  for (int lin = t; lin < 576 * 8; lin += 256) {      // 576 m x 8 uint4-chunks
    const int m = lin >> 3, ch = lin & 7;
    const int jj = m / 24, j = m - 24 * jj;
    unsigned short u8[8];
    #pragma unroll
    for (int u = 0; u < 8; ++u) {
      const int vv = ch * 8 + u;
      u8[u] = f2bf(JrS[vv][jj] * WtS[vv][j]);
    }
    *(uint4*)&GT[(size_t)m * VPAD + v0 + ch * 8] = *(uint4*)u8;
  }
}

// fp32-exact W[576] + JQ[11][72] via LDS-staged coalesced chunks + atomics.
// Grid 54 blocks of 128 vertices. W/JQ must be zeroed before launch.
__global__ __launch_bounds__(256) void k_wjq(const float* __restrict__ Jr,
                                             const float* __restrict__ wts,
                                             const float* __restrict__ vt,
                                             const float* __restrict__ sd,
                                             float* __restrict__ W,
                                             float* __restrict__ JQ) {
  __shared__ float JrS[128][24];
  __shared__ float WtS[128][24];
  __shared__ float SS[11][384];
  const int t  = threadIdx.x;
  const int v0 = blockIdx.x * 128;
  for (int lin = t; lin < 128 * 6; lin += 256) {
    const int row = lin / 6, q = lin - row * 6;
    const int v = v0 + row;
    float4 a = make_float4(0.f, 0.f, 0.f, 0.f), b = a;
    if (v < NV) {
      a = *(const float4*)(Jr  + (size_t)v * NJ + q * 4);
      b = *(const float4*)(wts + (size_t)v * NJ + q * 4);
    }
    *(float4*)&JrS[row][q * 4] = a;
    *(float4*)&WtS[row][q * 4] = b;
  }
  for (int lin = t; lin < 11 * 96; lin += 256) {
    const int r = lin / 96, q = lin - r * 96;
    const float* __restrict__ S = (r == 0) ? vt : (sd + (size_t)(r - 1) * 20670);
    float4 a = make_float4(0.f, 0.f, 0.f, 0.f);
    float* pa = (float*)&a;
    const int base = 3 * v0 + q * 4;
    if (base + 3 < 3 * NV) {
      a = *(const float4*)(S + base);
    } else {
      #pragma unroll
      for (int u = 0; u < 4; ++u) if (base + u < 3 * NV) pa[u] = S[base + u];
    }
    *(float4*)&SS[r][q * 4] = a;
  }
  __syncthreads();
  for (int m = t; m < 576; m += 256) {
    const int jj = m / 24, j = m - 24 * jj;
    float s = 0.f;
    for (int vv = 0; vv < 128; ++vv) s += JrS[vv][jj] * WtS[vv][j];
    atomicAdd(&W[m], s);
  }
  for (int o = t; o < 792; o += 256) {
    const int r = o / 72, tt = o - r * 72;
    const int j = tt / 3, c = tt - 3 * j;
    float s = 0.f;
    for (int vv = 0; vv < 128; ++vv) s += JrS[vv][j] * SS[r][vv * 3 + c];
    atomicAdd(&JQ[o], s);
  }
}

// P[z][m][n] = sum_v G[v][m]*D[v][n] via bf16 MFMA 16x16x32, fp32 acc.
// A and B both LDS-staged from bf16 GT/DT. Grid (11 n, 9 m, 10 z).
__global__ __launch_bounds__(256) void k_gemm1(const unsigned short* __restrict__ GT,
                                               const unsigned short* __restrict__ DT,
                                               float* __restrict__ P) {
  __shared__ unsigned short At[64][40];
  __shared__ unsigned short Bt[64][40];
  const int t = threadIdx.x;
  const int n0 = blockIdx.x * 64;
  const int m0 = blockIdx.y * 64;
  const int z  = blockIdx.z;
  const int kbeg = z * KCH;
  const int wv = t >> 6, lane = t & 63;
  const int quad = lane >> 4, l16 = lane & 15;
  const int srow = t >> 2, sch = t & 3;   // staging: row, k-chunk

  floatx4 acc[4] = {{0.f,0.f,0.f,0.f},{0.f,0.f,0.f,0.f},{0.f,0.f,0.f,0.f},{0.f,0.f,0.f,0.f}};
  for (int s = 0; s < 22; ++s) {
    const int k0 = kbeg + s * 32;
    *(uint4*)&At[srow][sch * 8] = *(const uint4*)&GT[(size_t)(m0 + srow) * VPAD + k0 + sch * 8];
    *(uint4*)&Bt[srow][sch * 8] = *(const uint4*)&DT[(size_t)(n0 + srow) * VPAD + k0 + sch * 8];
    __syncthreads();
    const short8 af = *(const short8*)&At[wv * 16 + l16][quad * 8];
    #pragma unroll
    for (int nf = 0; nf < 4; ++nf) {
      const short8 bf = *(const short8*)&Bt[nf * 16 + l16][quad * 8];
      acc[nf] = __builtin_amdgcn_mfma_f32_16x16x32_bf16(af, bf, acc[nf], 0, 0, 0);
    }
    __syncthreads();
  }
  // C/D layout (m89-verified): row m = quad*4 + reg, col n = lane&15
  float* __restrict__ Pz = P + (size_t)z * PSLAB;
  #pragma unroll
  for (int nf = 0; nf < 4; ++nf) {
    const int n_out = n0 + nf * 16 + l16;
    if (n_out < PPAD) {
      #pragma unroll
      for (int r = 0; r < 4; ++r) {
        const int m_out = m0 + wv * 16 + quad * 4 + r;
        Pz[(size_t)m_out * PPAD + n_out] = acc[nf][r];
      }
    }
  }
}

// sum the split-K partials into KQ
__global__ __launch_bounds__(256) void k_reduce(const float* __restrict__ P,
                                                float* __restrict__ KQ) {
  const int m = blockIdx.x;           // 0..575
  for (int n = threadIdx.x; n < NCOLR; n += 256) {
    float s = 0.f;
    #pragma unroll
    for (int zz = 0; zz < NZ; ++zz)
      s += P[(size_t)zz * PSLAB + (size_t)m * PPAD + n];
    const int rr = n / 3, c = n - 3 * rr;
    KQ[(size_t)rr * EDIM + m * 3 + c] = s;
  }
}

// per-batch Rodrigues + chain -> A[b][288], qT[r][b]
__global__ __launch_bounds__(64) void k_chain(const float* __restrict__ beta,
                                              const float* __restrict__ theta,
                                              const float* __restrict__ JQ,
                                              float* __restrict__ qT,
                                              float* __restrict__ A) {
  const int b = blockIdx.x;
  const int t = threadIdx.x;
  __shared__ float RES[24][12];
  __shared__ float Jl[24][3];
  const int par[24] = {-1,0,0,0,1,2,3,4,5,6,7,8,9,9,9,12,13,14,16,17,18,19,20,21};
  const int dep[24] = {0,1,1,1,2,2,2,3,3,3,4,4,4,4,4,5,5,5,6,6,7,7,8,8};
  float R[9];
  float Jv[3];
  if (t < 6) qT[(size_t)(NRQ + t) * NB + b] = 0.f;
  if (t < NJ) {
    const int j = t;
    const float th0 = theta[b * 72 + j * 3 + 0];
    const float th1 = theta[b * 72 + j * 3 + 1];
    const float th2 = theta[b * 72 + j * 3 + 2];
    const float a0 = th0 + 1e-8f, a1 = th1 + 1e-8f, a2 = th2 + 1e-8f;
    const float angle = sqrtf(a0 * a0 + a1 * a1 + a2 * a2);
    const float inv = 1.0f / angle;
    const float half = 0.5f * angle;
    const float cw = cosf(half), sv = sinf(half);
    float qw = cw, qx = sv * th0 * inv, qy = sv * th1 * inv, qz = sv * th2 * inv;
    const float qn = 1.0f / sqrtf(qw * qw + qx * qx + qy * qy + qz * qz);
    qw *= qn; qx *= qn; qy *= qn; qz *= qn;
    const float w2 = qw * qw, x2 = qx * qx, y2 = qy * qy, z2 = qz * qz;
    const float wx = qw * qx, wy = qw * qy, wz = qw * qz;
    const float xy = qx * qy, xz = qx * qz, yz = qy * qz;
    R[0] = w2 + x2 - y2 - z2; R[1] = 2.f * (xy - wz);   R[2] = 2.f * (xz + wy);
    R[3] = 2.f * (xy + wz);   R[4] = w2 - x2 + y2 - z2; R[5] = 2.f * (yz - wx);
    R[6] = 2.f * (xz - wy);   R[7] = 2.f * (yz + wx);   R[8] = w2 - x2 - y2 + z2;
    float betaf[10];
    #pragma unroll
    for (int s = 0; s < 10; ++s) betaf[s] = beta[b * 10 + s];
    #pragma unroll
    for (int c = 0; c < 3; ++c) {
      float jv = JQ[j * 3 + c];
      #pragma unroll
      for (int s = 0; s < 10; ++s) jv += betaf[s] * JQ[(1 + s) * 72 + j * 3 + c];
      Jv[c] = jv; Jl[j][c] = jv;
    }
    if (j >= 1) {
      #pragma unroll
      for (int k = 0; k < 9; ++k)
        qT[(size_t)(11 + (j - 1) * 9 + k) * NB + b] = R[k] - ((k == 0 || k == 4 || k == 8) ? 1.f : 0.f);
    }
    if (j == 0) qT[b] = 1.f;
    if (j < 10) qT[(size_t)(1 + j) * NB + b] = betaf[j];
  }
  __syncthreads();
  for (int lvl = 0; lvl < 9; ++lvl) {
    if (t < NJ && dep[t] == lvl) {
      if (t == 0) {
        #pragma unroll
        for (int i = 0; i < 3; ++i) {
          RES[0][i * 4 + 0] = R[i * 3 + 0]; RES[0][i * 4 + 1] = R[i * 3 + 1];
          RES[0][i * 4 + 2] = R[i * 3 + 2]; RES[0][i * 4 + 3] = Jv[i];
        }
      } else {
        const int p = par[t];
        const float tr0 = Jv[0] - Jl[p][0];
        const float tr1 = Jv[1] - Jl[p][1];
        const float tr2 = Jv[2] - Jl[p][2];
        float Pr[12];
        #pragma unroll
        for (int k = 0; k < 12; ++k) Pr[k] = RES[p][k];
        #pragma unroll
        for (int i = 0; i < 3; ++i) {
          const float r0 = Pr[i*4+0], r1 = Pr[i*4+1], r2 = Pr[i*4+2], r3 = Pr[i*4+3];
          RES[t][i * 4 + 0] = r0 * R[0] + r1 * R[3] + r2 * R[6];
          RES[t][i * 4 + 1] = r0 * R[1] + r1 * R[4] + r2 * R[7];
          RES[t][i * 4 + 2] = r0 * R[2] + r1 * R[5] + r2 * R[8];
          RES[t][i * 4 + 3] = r0 * tr0 + r1 * tr1 + r2 * tr2 + r3;
        }
      }
    }
    __syncthreads();
  }
  if (t < NJ) {
    float* Ab = A + (size_t)b * 288 + t * 12;
    #pragma unroll
    for (int i = 0; i < 3; ++i) {
      const float r0 = RES[t][i*4+0], r1 = RES[t][i*4+1], r2 = RES[t][i*4+2];
      const float ti = RES[t][i*4+3] - (r0 * Jv[0] + r1 * Jv[1] + r2 * Jv[2]);
      Ab[i*4+0] = r0; Ab[i*4+1] = r1; Ab[i*4+2] = r2; Ab[i*4+3] = ti;
    }
  }
}

// M[b][e] = sum_r qT[r][b] * KQ[r][e]
__global__ __launch_bounds__(256) void k_mgemm(const float* __restrict__ qT,
                                               const float* __restrict__ KQ,
                                               float* __restrict__ M) {
  __shared__ float Qs[16][64];
  __shared__ float Ks[16][64];
  const int t = threadIdx.x;
  const int e0 = blockIdx.x * 64;
  const int b0 = blockIdx.y * 64;
  const int tb = (t & 15) * 4;
  const int te = (t >> 4) * 4;
  const int skk = t >> 4;
  const int sc  = (t & 15) * 4;
  float acc[4][4] = {};
  for (int k0 = 0; k0 < QPAD; k0 += 16) {
    const int k = k0 + skk;
    *(float4*)&Qs[skk][sc] = *(const float4*)&qT[(size_t)k * NB + b0 + sc];
    if (k < NRQ) *(float4*)&Ks[skk][sc] = *(const float4*)&KQ[(size_t)k * EDIM + e0 + sc];
    else         *(float4*)&Ks[skk][sc] = make_float4(0.f, 0.f, 0.f, 0.f);
    __syncthreads();
    #pragma unroll
    for (int kk = 0; kk < 16; ++kk) {
      float4 qv = *(const float4*)&Qs[kk][tb];
      float4 kv = *(const float4*)&Ks[kk][te];
      const float qa[4] = {qv.x, qv.y, qv.z, qv.w};
      const float ka[4] = {kv.x, kv.y, kv.z, kv.w};
      #pragma unroll
      for (int i = 0; i < 4; ++i)
        #pragma unroll
        for (int j = 0; j < 4; ++j)
          acc[i][j] += qa[i] * ka[j];
    }
    __syncthreads();
  }
  #pragma unroll
  for (int i = 0; i < 4; ++i) {
    float4 st = make_float4(acc[i][0], acc[i][1], acc[i][2], acc[i][3]);
    *(float4*)&M[(size_t)(b0 + tb + i) * EDIM + e0 + te] = st;
  }
}

// joints[b,jj,i] = sum_j( A[b,j,i,:3] . M[b,(jj,j)*3..] + A[b,j,i,3]*W[jj,j] )
__global__ __launch_bounds__(256) void k_joints(const float* __restrict__ M,
                                                const float* __restrict__ A,
                                                const float* __restrict__ W,
                                                float* __restrict__ out) {
  const int b = blockIdx.x;
  const int t = threadIdx.x;
  __shared__ float Ml[EDIM];
  __shared__ float Al[288];
  __shared__ float Wl[576];
  {
    const float4* Mg = (const float4*)(M + (size_t)b * EDIM);
    float4* Ms = (float4*)Ml;
    for (int i = t; i < EDIM / 4; i += 256) Ms[i] = Mg[i];
    if (t < 72)  ((float4*)Al)[t] = ((const float4*)(A + (size_t)b * 288))[t];
    if (t < 144) ((float4*)Wl)[t] = ((const float4*)W)[t];
  }
  __syncthreads();
  if (t < 72) {
    const int jj = t / 3, i = t - jj * 3;
    float acc = 0.f;
    #pragma unroll
    for (int j = 0; j < NJ; ++j) {
      const float* Ar = &Al[j * 12 + i * 4];
      const int base = (jj * NJ + j) * 3;
      acc += Ar[0] * Ml[base] + Ar[1] * Ml[base + 1]
           + Ar[2] * Ml[base + 2] + Ar[3] * Wl[jj * NJ + j];
    }
    out[(size_t)b * 72 + t] = acc;
  }
}

// =================== fallback: validated monolithic kernel (R5) ===================
__global__ __launch_bounds__(256) void k_all(
    const float* __restrict__ beta,
    const float* __restrict__ theta,
    const float* __restrict__ vt,
    const float* __restrict__ sd,
    const float* __restrict__ pd,
    const float* __restrict__ Jr,
    const float* __restrict__ wts,
    float* __restrict__ out) {
  const int b = blockIdx.x;
  const int t = threadIdx.x;
  __shared__ float vs[NV * 3];
  __shared__ float bl[10];
  __shared__ float pf[207];
  __shared__ float Am[NJ * 12];
  __shared__ float Jl[NJ * 3];
  __shared__ float jpart[72 * 3];
  __shared__ float jred[72];
  if (t < 10) bl[t] = beta[b * 10 + t];
  if (t < 72) jred[t] = 0.f;
  __syncthreads();
  for (int e = t; e < NV * 3; e += 256) {
    float val = vt[e];
    #pragma unroll
    for (int s = 0; s < 10; ++s) val += bl[s] * sd[s * 20670 + e];
    vs[e] = val;
  }
  __syncthreads();
  if (t < 216) {
    const int o = t % 72, part = t / 72;
    const int j = o / 3, c = o - j * 3;
    float local = 0.f;
    for (int v = part; v < NV; v += 3)
      local += Jr[v * NJ + j] * vs[v * 3 + c];
    jpart[o * 3 + part] = local;
  }
  __syncthreads();
  if (t < 72) Jl[t] = jpart[t * 3] + jpart[t * 3 + 1] + jpart[t * 3 + 2];
  __syncthreads();
  const int par[24] = {-1,0,0,0,1,2,3,4,5,6,7,8,9,9,9,12,13,14,16,17,18,19,20,21};
  const int dep[24] = {0,1,1,1,2,2,2,3,3,3,4,4,4,4,4,5,5,5,6,6,7,7,8,8};
  float R[9];
  float Jv[3];
  if (t < NJ) {
    const int j = t;
    const float th0 = theta[b * 72 + j * 3 + 0];
    const float th1 = theta[b * 72 + j * 3 + 1];
    const float th2 = theta[b * 72 + j * 3 + 2];
    const float a0 = th0 + 1e-8f, a1 = th1 + 1e-8f, a2 = th2 + 1e-8f;
    const float angle = sqrtf(a0 * a0 + a1 * a1 + a2 * a2);
    const float inv = 1.0f / angle;
    const float half = 0.5f * angle;
    const float cw = cosf(half), sv = sinf(half);
    float qw = cw, qx = sv * th0 * inv, qy = sv * th1 * inv, qz = sv * th2 * inv;
    const float qn = 1.0f / sqrtf(qw * qw + qx * qx + qy * qy + qz * qz);
    qw *= qn; qx *= qn; qy *= qn; qz *= qn;
    const float w2 = qw * qw, x2 = qx * qx, y2 = qy * qy, z2 = qz * qz;
    const float wx = qw * qx, wy = qw * qy, wz = qw * qz;
    const float xy = qx * qy, xz = qx * qz, yz = qy * qz;
    R[0] = w2 + x2 - y2 - z2; R[1] = 2.f * (xy - wz);   R[2] = 2.f * (xz + wy);
    R[3] = 2.f * (xy + wz);   R[4] = w2 - x2 + y2 - z2; R[5] = 2.f * (yz - wx);
    R[6] = 2.f * (xz - wy);   R[7] = 2.f * (yz + wx);   R[8] = w2 - x2 - y2 + z2;
    #pragma unroll
    for (int c = 0; c < 3; ++c) Jv[c] = Jl[j * 3 + c];
    if (j >= 1) {
      #pragma unroll
      for (int k = 0; k < 9; ++k)
        pf[(j - 1) * 9 + k] = R[k] - ((k == 0 || k == 4 || k == 8) ? 1.f : 0.f);
    }
  }
  __syncthreads();
  for (int lvl = 0; lvl < 9; ++lvl) {
    if (t < NJ && dep[t] == lvl) {
      if (t == 0) {
        #pragma unroll
        for (int i = 0; i < 3; ++i) {
          Am[i * 4 + 0] = R[i * 3 + 0]; Am[i * 4 + 1] = R[i * 3 + 1];
          Am[i * 4 + 2] = R[i * 3 + 2]; Am[i * 4 + 3] = Jv[i];
        }
      } else {
        const int p = par[t];
        const float tr0 = Jv[0] - Jl[p * 3 + 0];
        const float tr1 = Jv[1] - Jl[p * 3 + 1];
        const float tr2 = Jv[2] - Jl[p * 3 + 2];
        float Pr[12];
        #pragma unroll
        for (int k = 0; k < 12; ++k) Pr[k] = Am[p * 12 + k];
        #pragma unroll
        for (int i = 0; i < 3; ++i) {
          const float r0 = Pr[i*4+0], r1 = Pr[i*4+1], r2 = Pr[i*4+2], r3 = Pr[i*4+3];
          Am[t * 12 + i * 4 + 0] = r0 * R[0] + r1 * R[3] + r2 * R[6];
          Am[t * 12 + i * 4 + 1] = r0 * R[1] + r1 * R[4] + r2 * R[7];
          Am[t * 12 + i * 4 + 2] = r0 * R[2] + r1 * R[5] + r2 * R[8];
          Am[t * 12 + i * 4 + 3] = r0 * tr0 + r1 * tr1 + r2 * tr2 + r3;
        }
      }
    }
    __syncthreads();
  }
  if (t < NJ) {
    float res[12];
    #pragma unroll
    for (int k = 0; k < 12; ++k) res[k] = Am[t * 12 + k];
    #pragma unroll
    for (int i = 0; i < 3; ++i) {
      const float r0 = res[i * 4 + 0], r1 = res[i * 4 + 1], r2 = res[i * 4 + 2];
      Am[t * 12 + i * 4 + 3] = res[i * 4 + 3] - (r0 * Jv[0] + r1 * Jv[1] + r2 * Jv[2]);
    }
  }
  __syncthreads();
  for (int r = 0; r < 207; ++r) {
    const float f = pf[r];
    const float* __restrict__ pr = pd + (size_t)r * 20670;
    for (int e = t; e < NV * 3; e += 256) vs[e] += f * pr[e];
  }
  __syncthreads();
  float jacc[72];
  #pragma unroll
  for (int k = 0; k < 72; ++k) jacc[k] = 0.f;
  for (int v = t; v < NV; v += 256) {
    const float vp0 = vs[3 * v + 0];
    const float vp1 = vs[3 * v + 1];
    const float vp2 = vs[3 * v + 2];
    float tA[12];
    #pragma unroll
    for (int k = 0; k < 12; ++k) tA[k] = 0.f;
    const float* __restrict__ wp = wts + (size_t)v * NJ;
    #pragma unroll
    for (int j = 0; j < NJ; ++j) {
      const float wj = wp[j];
      #pragma unroll
      for (int k = 0; k < 12; ++k) tA[k] += wj * Am[j * 12 + k];
    }
    const float vx = tA[0] * vp0 + tA[1] * vp1 + tA[2]  * vp2 + tA[3];
    const float vy = tA[4] * vp0 + tA[5] * vp1 + tA[6]  * vp2 + tA[7];
    const float vz = tA[8] * vp0 + tA[9] * vp1 + tA[10] * vp2 + tA[11];
    const float* __restrict__ jp = Jr + (size_t)v * NJ;
    #pragma unroll
    for (int jj = 0; jj < NJ; ++jj) {
      const float g = jp[jj];
      jacc[jj * 3 + 0] += g * vx;
      jacc[jj * 3 + 1] += g * vy;
      jacc[jj * 3 + 2] += g * vz;
    }
  }
  #pragma unroll
  for (int k = 0; k < 72; ++k) atomicAdd(&jred[k], jacc[k]);
  __syncthreads();
  if (t < 72) out[(size_t)b * 72 + t] = jred[t];
}

extern "C" void kernel_launch(void* const* d_in, const int* in_sizes, int n_in,
                              void* d_out, int out_size, void* d_ws, size_t ws_size,
                              hipStream_t stream) {
  const float* beta  = (const float*)d_in[0];
  const float* theta = (const float*)d_in[1];
  const float* vt    = (const float*)d_in[2];
  const float* sd    = (const float*)d_in[3];
  const float* pd    = (const float*)d_in[4];
  const float* Jr    = (const float*)d_in[5];
  const float* wts   = (const float*)d_in[6];
  float* out = (float*)d_out;
  (void)in_sizes; (void)n_in; (void)out_size;

  if (ws_size >= TOTAL_WS) {
    char* ws = (char*)d_ws;
    float* P  = (float*)(ws + OFF_P);
    unsigned short* DT = (unsigned short*)(ws + OFF_D);
    unsigned short* GT = (unsigned short*)(ws + OFF_GT);
    float* KQ = (float*)(ws + OFF_KQ);
    float* W  = (float*)(ws + OFF_W);
    float* JQ = (float*)(ws + OFF_JQ);
    float* qT = (float*)(ws + OFF_Q);
    float* A  = (float*)(ws + OFF_A);
    float* M  = (float*)(ws + OFF_M);   // aliases P (P dead after k_reduce)

    hipMemsetAsync(ws + OFF_W, 0, 5504, stream);   // zero W + JQ for atomics
    k_dfill<<<dim3(VPAD / 64, 10), 256, 0, stream>>>(vt, sd, pd, DT);
    k_gfill<<<VPAD / 64, 256, 0, stream>>>(Jr, wts, GT);
    k_wjq<<<(NV + 127) / 128, 256, 0, stream>>>(Jr, wts, vt, sd, W, JQ);
    k_gemm1<<<dim3(11, 9, NZ), 256, 0, stream>>>(GT, DT, P);
    k_reduce<<<MROWS, 256, 0, stream>>>(P, KQ);
    k_chain<<<NB, 64, 0, stream>>>(beta, theta, JQ, qT, A);
    k_mgemm<<<dim3(27, 16), 256, 0, stream>>>(qT, KQ, M);
    k_joints<<<NB, 256, 0, stream>>>(M, A, W, out);
  } else {
    k_all<<<NB, 256, 0, stream>>>(beta, theta, vt, sd, pd, Jr, wts, out);
  }
}